// Round 12
// baseline (507.486 us; speedup 1.0000x reference)
//
#include <hip/hip_runtime.h>

// RandomProjectionQuantizer: x(16,3000,80) f32, proj(320,16) f32, codebook(8192,16) f32
// out: argmin indices (16,750) int32.  STACK=4, 3000%4==0 -> no padding.
//
// Round-12 design notes (evidence-driven):
//  - Round 11: rpq_main 61.4us, VGPR=120, no spill, BUT occupancy pinned at 18.3%
//    despite 32 KB LDS (hw permits 4 blocks/CU). Hypothesis: waves_per_eu MAX caps
//    residency. Test: (3,3) -> budget 170 >> 120 live (safe headroom, unlike the
//    round-9/10 collapses where budget ~= live).
//  - ~81us lived OUTSIDE rpq_main every round. prep_xp (188 blocks x 64thr) was
//    latency-bound near-serial. Redesign: thread=(row,p), 750 blocks, proj
//    transposed into LDS (stride 324 floats -> 16B-aligned cols, 2-way max bank
//    aliasing = free), both operands b128. fma chain + 16-wide butterfly are
//    bit-identical to the round-2..8-validated path.
//  - Launch-count 4 -> 2 (+1 memset node): prep_cb/prep_xp fused by block range;
//    rpq_reduce folded into rpq_main via decoupled last-block pattern
//    (threadfence release/acquire + atomicAdd counter; cnt zeroed by memsetAsync).
//  - Main-kernel inner loop byte-identical to round 11 (validated 61.4us, spill-free).

#define ROWS   12000   // 16 * 750
#define DIN    320     // 80 * 4
#define PD     16      // proj_dim
#define NCODES 8192

#define NSL    16             // code slices across blocks
#define SLC    (NCODES/NSL)   // 512 codes per slice (32 KB LDS)
#define RT     6              // rows per thread
#define RPB    48             // rows per block = 8 rs-groups * RT
#define NRG    (ROWS/RPB)     // 250 row-groups
#define GRID   (NRG*NSL)      // 4000 blocks

#define CBBLK  512            // prep blocks doing codebook work
#define XPBLK  750            // prep blocks doing projection work (16 rows each)
#define PSTR   324            // LDS proj column stride (floats): 16B-aligned, 2-way banks

typedef unsigned long long u64;

// ---------------- fused prep: codebook normalize+relayout | projection+normalize ----------------
__global__ __launch_bounds__(256) void prep_fused(const float* __restrict__ cb,
                                                  const float* __restrict__ proj,
                                                  const float* __restrict__ x,
                                                  float* __restrict__ cbt,
                                                  float* __restrict__ xp) {
    __shared__ __align__(16) float ldsT[PD * PSTR];   // 20.25 KiB (xp path only)
    const int b = blockIdx.x, tid = threadIdx.x;

    if (b < CBBLK) {
        // ---- codebook normalize + quarter-major slice relayout (validated x7) ----
        int gt = b * 256 + tid;                        // 131072 = 8192*16
        int n = gt >> 4, p = gt & 15;
        float v = cb[gt];
        float ss = v * v;
        ss += __shfl_xor(ss, 1, 16);
        ss += __shfl_xor(ss, 2, 16);
        ss += __shfl_xor(ss, 4, 16);
        ss += __shfl_xor(ss, 8, 16);
        float nrm = fmaxf(sqrtf(ss), 1e-12f);
        int s = n >> 9, cl = n & 511, q = p >> 2, j = p & 3;
        cbt[s * 8192 + q * 2048 + cl * 4 + j] = v / nrm;
    } else {
        // ---- projection + normalize: thread=(row,p), proj transposed in LDS ----
        // Numerics bit-identical to rounds 2-8: per-(r,p) fma over k ascending,
        // 16-wide shfl_xor butterfly, store acc / fmaxf(sqrtf(ss),1e-12).
#pragma unroll
        for (int it = 0; it < 20; ++it) {              // 5120 floats, coalesced reads
            int g = it * 256 + tid;
            ldsT[(g & 15) * PSTR + (g >> 4)] = proj[g];
        }
        __syncthreads();

        const int r = (b - CBBLK) * 16 + (tid >> 4);
        const int p = tid & 15;
        const float4* xr = reinterpret_cast<const float4*>(x + (size_t)r * DIN);
        const float4* pc = reinterpret_cast<const float4*>(ldsT + p * PSTR); // p*1296B, 16B-aligned

        float acc = 0.f;
#pragma unroll 4
        for (int k4 = 0; k4 < DIN / 4; ++k4) {
            float4 xv = xr[k4];
            float4 pv = pc[k4];
            acc = fmaf(xv.x, pv.x, acc);
            acc = fmaf(xv.y, pv.y, acc);
            acc = fmaf(xv.z, pv.z, acc);
            acc = fmaf(xv.w, pv.w, acc);
        }
        float ss = acc * acc;
        ss += __shfl_xor(ss, 1, 16);
        ss += __shfl_xor(ss, 2, 16);
        ss += __shfl_xor(ss, 4, 16);
        ss += __shfl_xor(ss, 8, 16);
        xp[r * PD + p] = acc / fmaxf(sqrtf(ss), 1e-12f);
    }
}

// ---------------- fused scores + partial argmin + last-block final reduce ----------------
__global__ __launch_bounds__(256)
__attribute__((amdgpu_waves_per_eu(3, 3)))      // round-11 (2,2) pinned occupancy at 18%;
                                                // budget 512/3=170 >> 120 live -> no spill
void rpq_main(const float* __restrict__ xp,
              const float* __restrict__ cbt,
              u64* __restrict__ keys,
              unsigned* __restrict__ cnt,
              int* __restrict__ out) {
    __shared__ __align__(16) float4 lds4[SLC * PD / 4];   // 2048 float4 = 32 KiB
    __shared__ unsigned dflag;

    const int tid   = threadIdx.x;
    const int cs    = tid & 31;          // code lane (round-8/11 geometry)
    const int rs    = tid >> 5;          // row group 0..7
    const int slice = blockIdx.x & (NSL - 1);
    const int rg    = blockIdx.x >> 4;
    const int row0  = rg * RPB + rs * RT;

    // stage the whole 32 KiB slice once: identity copy, conflict-free
    {
        const float4* src = reinterpret_cast<const float4*>(cbt) + (size_t)slice * (SLC * PD / 4);
#pragma unroll
        for (int it = 0; it < 8; ++it)
            lds4[it * 256 + tid] = src[it * 256 + tid];
    }

    // per-thread xp fragment: RT rows x 4 float4 quarters (static indexing)
    float4 xq[RT][4];
#pragma unroll
    for (int r = 0; r < RT; ++r) {
        const float4* s4 = reinterpret_cast<const float4*>(xp + (size_t)(row0 + r) * PD);
#pragma unroll
        for (int q = 0; q < 4; ++q) xq[r][q] = s4[q];
    }

    float bd[RT];
    int   bi[RT];
#pragma unroll
    for (int r = 0; r < RT; ++r) { bd[r] = 3.0e38f; bi[r] = 0; }

    __syncthreads();                     // slice staged

    const float4* base = lds4 + cs;      // one base reg; q,i become imm offsets (<32 KiB)
    const int code_base = slice * SLC;

#pragma unroll 4
    for (int i = 0; i < SLC / 32; ++i) {             // 16 iters, unroll-4 window (validated)
        const float4 c0 = base[i * 32 +    0];       // quarter 0
        const float4 c1 = base[i * 32 +  512];       // quarter 1
        const float4 c2 = base[i * 32 + 1024];       // quarter 2
        const float4 c3 = base[i * 32 + 1536];       // quarter 3
        const int gcode = code_base + i * 32 + cs;
#pragma unroll
        for (int r = 0; r < RT; ++r) {
            float s = 0.f;                            // k-order chain identical to rounds 2-11
            s = fmaf(xq[r][0].x, c0.x, s); s = fmaf(xq[r][0].y, c0.y, s);
            s = fmaf(xq[r][0].z, c0.z, s); s = fmaf(xq[r][0].w, c0.w, s);
            s = fmaf(xq[r][1].x, c1.x, s); s = fmaf(xq[r][1].y, c1.y, s);
            s = fmaf(xq[r][1].z, c1.z, s); s = fmaf(xq[r][1].w, c1.w, s);
            s = fmaf(xq[r][2].x, c2.x, s); s = fmaf(xq[r][2].y, c2.y, s);
            s = fmaf(xq[r][2].z, c2.z, s); s = fmaf(xq[r][2].w, c2.w, s);
            s = fmaf(xq[r][3].x, c3.x, s); s = fmaf(xq[r][3].y, c3.y, s);
            s = fmaf(xq[r][3].z, c3.z, s); s = fmaf(xq[r][3].w, c3.w, s);
            float dd = 2.0f - 2.0f * s;               // same formula/codegen as validated rounds
            if (dd < bd[r]) { bd[r] = dd; bi[r] = gcode; }   // strict <, ascending codes
        }
    }

    // reduce across the 32 code-lanes of each row group, write partial key (validated)
#pragma unroll
    for (int r = 0; r < RT; ++r) {
        unsigned ub = __float_as_uint(bd[r]);
        ub = (ub & 0x80000000u) ? ~ub : (ub | 0x80000000u);   // monotone total order
        u64 key = ((u64)ub << 32) | (unsigned)bi[r];
#pragma unroll
        for (int off = 16; off >= 1; off >>= 1) {
            u64 o = __shfl_xor(key, off, 32);
            key = (o < key) ? o : key;                // min dist, tie -> min index
        }
        if (cs == 0) keys[(size_t)slice * ROWS + row0 + r] = key;
    }

    // ---- decoupled last-block final reduce (replaces rpq_reduce launch) ----
    __threadfence();                     // release: keys visible device-wide
    __syncthreads();                     // all lanes' stores issued before the bump
    if (tid == 0)
        dflag = (atomicAdd(&cnt[rg], 1u) == NSL - 1) ? 1u : 0u;
    __syncthreads();
    if (dflag) {
        __threadfence();                 // acquire: see all 16 slices' keys
        if (tid < RPB) {
            int row = rg * RPB + tid;
            u64 m = keys[row];
#pragma unroll
            for (int s2 = 1; s2 < NSL; ++s2) {
                u64 o = keys[(size_t)s2 * ROWS + row];
                m = (o < m) ? o : m;
            }
            out[row] = (int)(m & 0xFFFFFFFFu);
        }
    }
}

extern "C" void kernel_launch(void* const* d_in, const int* in_sizes, int n_in,
                              void* d_out, int out_size, void* d_ws, size_t ws_size,
                              hipStream_t stream) {
    const float* x    = (const float*)d_in[0];   // 16*3000*80
    const float* proj = (const float*)d_in[1];   // 320*16
    const float* cb   = (const float*)d_in[2];   // 8192*16
    int* out = (int*)d_out;                      // 12000 int32

    float*    cbt  = (float*)d_ws;                                  // 512 KiB @ 0
    float*    xp   = (float*)((char*)d_ws + 524288);                // 768 KiB
    u64*      keys = (u64*)  ((char*)d_ws + 524288 + 786432);       // 1.5 MiB
    unsigned* cnt  = (unsigned*)((char*)d_ws + 524288 + 786432 + 1536000); // 1000 B

    hipMemsetAsync(cnt, 0, NRG * sizeof(unsigned), stream);         // capturable node
    prep_fused<<<CBBLK + XPBLK, 256, 0, stream>>>(cb, proj, x, cbt, xp);
    rpq_main<<<GRID, 256, 0, stream>>>(xp, cbt, keys, cnt, out);
}

// Round 14
// 123.212 us; speedup vs baseline: 4.1188x; 4.1188x over previous
//
#include <hip/hip_runtime.h>

// RandomProjectionQuantizer: x(16,3000,80) f32, proj(320,16) f32, codebook(8192,16) f32
// out: argmin indices (16,750) int32.  STACK=4, 3000%4==0 -> no padding.
//
// Round-13 design notes (evidence-driven):
//  - Round 12: decoupled last-block reduce w/ __threadfence = cross-XCD L2
//    flush per block -> 479us of serialized stall (VALUBusy 8%). REMOVED.
//    Lesson: no device-scope fences in hot kernels on multi-XCD parts.
//  - Allocator model (rounds 4,5,9,10,11,12): VGPR budget = 512/(2*min_waves_per_eu).
//    min=4 -> 64, min=3 -> 84, min=2 -> 120/128. Round-11 occupancy (18%) was
//    capped by the (2,2) MAX, not resources. Fix: waves_per_eu(2,4) -> allocator
//    budget 128 (>= 120 live, no spill), residency cap 4 blocks/CU.
//  - prep_fused kept (round 12: non-main time 81 -> 28us, absmax 0.0).
//  - rpq_main body byte-identical to round 11 (61.4us validated, spill-free);
//    separate rpq_reduce launch (round-11-validated).

#define ROWS   12000   // 16 * 750
#define DIN    320     // 80 * 4
#define PD     16      // proj_dim
#define NCODES 8192

#define NSL    16             // code slices across blocks
#define SLC    (NCODES/NSL)   // 512 codes per slice (32 KB LDS)
#define RT     6              // rows per thread
#define RPB    48             // rows per block = 8 rs-groups * RT
#define NRG    (ROWS/RPB)     // 250 row-groups
#define GRID   (NRG*NSL)      // 4000 blocks

#define CBBLK  512            // prep blocks doing codebook work
#define XPBLK  750            // prep blocks doing projection work (16 rows each)
#define PSTR   324            // LDS proj column stride (floats): 16B-aligned, 2-way banks

typedef unsigned long long u64;

// ---------------- fused prep: codebook normalize+relayout | projection+normalize ----------------
// (byte-identical to round 12, validated absmax 0.0)
__global__ __launch_bounds__(256) void prep_fused(const float* __restrict__ cb,
                                                  const float* __restrict__ proj,
                                                  const float* __restrict__ x,
                                                  float* __restrict__ cbt,
                                                  float* __restrict__ xp) {
    __shared__ __align__(16) float ldsT[PD * PSTR];   // 20.25 KiB (xp path only)
    const int b = blockIdx.x, tid = threadIdx.x;

    if (b < CBBLK) {
        // ---- codebook normalize + quarter-major slice relayout (validated x8) ----
        int gt = b * 256 + tid;                        // 131072 = 8192*16
        int n = gt >> 4, p = gt & 15;
        float v = cb[gt];
        float ss = v * v;
        ss += __shfl_xor(ss, 1, 16);
        ss += __shfl_xor(ss, 2, 16);
        ss += __shfl_xor(ss, 4, 16);
        ss += __shfl_xor(ss, 8, 16);
        float nrm = fmaxf(sqrtf(ss), 1e-12f);
        int s = n >> 9, cl = n & 511, q = p >> 2, j = p & 3;
        cbt[s * 8192 + q * 2048 + cl * 4 + j] = v / nrm;
    } else {
        // ---- projection + normalize: thread=(row,p), proj transposed in LDS ----
        // Numerics bit-identical to rounds 2-8: per-(r,p) fma over k ascending,
        // 16-wide shfl_xor butterfly, store acc / fmaxf(sqrtf(ss),1e-12).
#pragma unroll
        for (int it = 0; it < 20; ++it) {              // 5120 floats, coalesced reads
            int g = it * 256 + tid;
            ldsT[(g & 15) * PSTR + (g >> 4)] = proj[g];
        }
        __syncthreads();

        const int r = (b - CBBLK) * 16 + (tid >> 4);
        const int p = tid & 15;
        const float4* xr = reinterpret_cast<const float4*>(x + (size_t)r * DIN);
        const float4* pc = reinterpret_cast<const float4*>(ldsT + p * PSTR); // 16B-aligned

        float acc = 0.f;
#pragma unroll 4
        for (int k4 = 0; k4 < DIN / 4; ++k4) {
            float4 xv = xr[k4];
            float4 pv = pc[k4];
            acc = fmaf(xv.x, pv.x, acc);
            acc = fmaf(xv.y, pv.y, acc);
            acc = fmaf(xv.z, pv.z, acc);
            acc = fmaf(xv.w, pv.w, acc);
        }
        float ss = acc * acc;
        ss += __shfl_xor(ss, 1, 16);
        ss += __shfl_xor(ss, 2, 16);
        ss += __shfl_xor(ss, 4, 16);
        ss += __shfl_xor(ss, 8, 16);
        xp[r * PD + p] = acc / fmaxf(sqrtf(ss), 1e-12f);
    }
}

// ---------------- fused scores + partial argmin ----------------
// Body byte-identical to round 11 (61.4us, VGPR=120, zero spill). ONE change:
// waves_per_eu (2,2)->(2,4): allocator budget keys off min (=2 -> 128 regs,
// validated), residency cap rises to 4 blocks/CU.
__global__ __launch_bounds__(256)
__attribute__((amdgpu_waves_per_eu(2, 4)))
void rpq_main(const float* __restrict__ xp,
              const float* __restrict__ cbt,
              u64* __restrict__ keys) {
    __shared__ __align__(16) float4 lds4[SLC * PD / 4];   // 2048 float4 = 32 KiB

    const int tid   = threadIdx.x;
    const int cs    = tid & 31;          // code lane (round-8/11 geometry)
    const int rs    = tid >> 5;          // row group 0..7
    const int slice = blockIdx.x & (NSL - 1);
    const int rg    = blockIdx.x >> 4;
    const int row0  = rg * RPB + rs * RT;

    // stage the whole 32 KiB slice once: identity copy, conflict-free
    {
        const float4* src = reinterpret_cast<const float4*>(cbt) + (size_t)slice * (SLC * PD / 4);
#pragma unroll
        for (int it = 0; it < 8; ++it)
            lds4[it * 256 + tid] = src[it * 256 + tid];
    }

    // per-thread xp fragment: RT rows x 4 float4 quarters (static indexing)
    float4 xq[RT][4];
#pragma unroll
    for (int r = 0; r < RT; ++r) {
        const float4* s4 = reinterpret_cast<const float4*>(xp + (size_t)(row0 + r) * PD);
#pragma unroll
        for (int q = 0; q < 4; ++q) xq[r][q] = s4[q];
    }

    float bd[RT];
    int   bi[RT];
#pragma unroll
    for (int r = 0; r < RT; ++r) { bd[r] = 3.0e38f; bi[r] = 0; }

    __syncthreads();                     // slice staged (only barrier before epilogue)

    const float4* base = lds4 + cs;      // one base reg; q,i become imm offsets (<32 KiB)
    const int code_base = slice * SLC;

#pragma unroll 4
    for (int i = 0; i < SLC / 32; ++i) {             // 16 iters, unroll-4 window (validated)
        const float4 c0 = base[i * 32 +    0];       // quarter 0
        const float4 c1 = base[i * 32 +  512];       // quarter 1
        const float4 c2 = base[i * 32 + 1024];       // quarter 2
        const float4 c3 = base[i * 32 + 1536];       // quarter 3
        const int gcode = code_base + i * 32 + cs;
#pragma unroll
        for (int r = 0; r < RT; ++r) {
            float s = 0.f;                            // k-order chain identical to rounds 2-12
            s = fmaf(xq[r][0].x, c0.x, s); s = fmaf(xq[r][0].y, c0.y, s);
            s = fmaf(xq[r][0].z, c0.z, s); s = fmaf(xq[r][0].w, c0.w, s);
            s = fmaf(xq[r][1].x, c1.x, s); s = fmaf(xq[r][1].y, c1.y, s);
            s = fmaf(xq[r][1].z, c1.z, s); s = fmaf(xq[r][1].w, c1.w, s);
            s = fmaf(xq[r][2].x, c2.x, s); s = fmaf(xq[r][2].y, c2.y, s);
            s = fmaf(xq[r][2].z, c2.z, s); s = fmaf(xq[r][2].w, c2.w, s);
            s = fmaf(xq[r][3].x, c3.x, s); s = fmaf(xq[r][3].y, c3.y, s);
            s = fmaf(xq[r][3].z, c3.z, s); s = fmaf(xq[r][3].w, c3.w, s);
            float dd = 2.0f - 2.0f * s;               // same formula/codegen as validated rounds
            if (dd < bd[r]) { bd[r] = dd; bi[r] = gcode; }   // strict <, ascending codes
        }
    }

    // reduce across the 32 code-lanes of each row group, write partial key (validated)
#pragma unroll
    for (int r = 0; r < RT; ++r) {
        unsigned ub = __float_as_uint(bd[r]);
        ub = (ub & 0x80000000u) ? ~ub : (ub | 0x80000000u);   // monotone total order
        u64 key = ((u64)ub << 32) | (unsigned)bi[r];
#pragma unroll
        for (int off = 16; off >= 1; off >>= 1) {
            u64 o = __shfl_xor(key, off, 32);
            key = (o < key) ? o : key;                // min dist, tie -> min index
        }
        if (cs == 0) keys[(size_t)slice * ROWS + row0 + r] = key;
    }
}

// ---------------- final reduce over NSL partials (round-11-validated) ----------------
__global__ __launch_bounds__(256) void rpq_reduce(const u64* __restrict__ keys,
                                                  int* __restrict__ out) {
    int r = blockIdx.x * 256 + threadIdx.x;
    if (r >= ROWS) return;
    u64 m = keys[r];
#pragma unroll
    for (int s = 1; s < NSL; ++s) {
        u64 o = keys[(size_t)s * ROWS + r];
        m = (o < m) ? o : m;
    }
    out[r] = (int)(m & 0xFFFFFFFFu);
}

extern "C" void kernel_launch(void* const* d_in, const int* in_sizes, int n_in,
                              void* d_out, int out_size, void* d_ws, size_t ws_size,
                              hipStream_t stream) {
    const float* x    = (const float*)d_in[0];   // 16*3000*80
    const float* proj = (const float*)d_in[1];   // 320*16
    const float* cb   = (const float*)d_in[2];   // 8192*16
    int* out = (int*)d_out;                      // 12000 int32

    float* cbt  = (float*)d_ws;                                    // 512 KiB @ 0
    float* xp   = (float*)((char*)d_ws + 524288);                  // 768 KiB
    u64*   keys = (u64*)  ((char*)d_ws + 524288 + 786432);         // 1.5 MiB (16 slices)

    prep_fused<<<CBBLK + XPBLK, 256, 0, stream>>>(cb, proj, x, cbt, xp);
    rpq_main<<<GRID, 256, 0, stream>>>(xp, cbt, keys);
    rpq_reduce<<<(ROWS + 255) / 256, 256, 0, stream>>>(keys, out);
}